// Round 4
// baseline (137.614 us; speedup 1.0000x reference)
//
#include <hip/hip_runtime.h>

#define BN_EPS 1e-5f

typedef _Float16 half8 __attribute__((ext_vector_type(8)));
typedef float f32x4 __attribute__((ext_vector_type(4)));

__device__ __forceinline__ float tanh_fast(float x){
  float e = __expf(2.0f * x);
  return 1.0f - 2.0f / (e + 1.0f);
}

// ---------------- prep: W1 -> fp16 in MFMA-fragment order + BN scale/shift ----------------
// Fragment (q,c): q = k-chunk (32 k each, 0..7), c = col-block (16 e each, 0..15).
// lane l = kg*16+lr holds 8 halves: e = c*16+lr, d = q*32+kg*8+j.
__global__ __launch_bounds__(256) void k_prep(const float* __restrict__ W1,
    const float* __restrict__ gamma, const float* __restrict__ beta,
    const float* __restrict__ rmean, const float* __restrict__ rvar,
    _Float16* __restrict__ Bp2, float* __restrict__ bns, float* __restrict__ bnb){
  int i = blockIdx.x * 256 + threadIdx.x;   // 0..65535
  int j  = i & 7;
  int l  = (i >> 3) & 63;
  int c  = (i >> 9) & 15;
  int q  = (i >> 13) & 7;
  int lr = l & 15, kg = l >> 4;
  int e  = c * 16 + lr;
  int d  = q * 32 + kg * 8 + j;
  Bp2[i] = (_Float16)W1[e * 256 + d];
  if (i < 4096){
    float sc = gamma[i] * rsqrtf(rvar[i] + BN_EPS);
    bns[i] = sc;
    bnb[i] = beta[i] - rmean[i] * sc;
  }
}

// ---------------- fused GEMM + BN + tanh + dot(x_h) + local softmax + weighted tile sum ----------------
// 512 thr (8 waves), tile BM=128 s-rows x BN=256 e-cols, K=256, BK=64 (4 steps).
// A tile: FULL 128x256 fp16 in LDS, XOR-swizzled (byte ^= (row&7)<<4), K-steps fill
// disjoint column ranges so the tile survives for the weighted-sum epilogue.
// B: register-direct coalesced fragment loads from L2 (fragment-ordered Bp).
// Outputs per (b, chunk): m_c, z_c, P_c[256] = sum_s exp(a_t-m_c) * x[s,:].
__global__ __launch_bounds__(512) void k_fused(const float* __restrict__ xh,
    const float* __restrict__ xhpre, const _Float16* __restrict__ Bp,
    const float* __restrict__ bns, const float* __restrict__ bnb,
    float* __restrict__ Pbuf, float2* __restrict__ mz){
  constexpr int S = 4096, Dd = 256;
  const int bid = blockIdx.x;       // 64 b * 32 chunks
  const int b  = bid >> 5;
  const int s0 = (bid & 31) * 128;
  const int tid = threadIdx.x;
  const int lane = tid & 63;
  const int w = tid >> 6;
  const int wm = w >> 2, wn = w & 3;
  const int kg = lane >> 4;      // 0..3
  const int lr = lane & 15;      // 0..15

  __shared__ _Float16 A[128 * 256];          // 64 KB, XOR-swizzled rows
  __shared__ float bnsc[128], bnsh[128];
  __shared__ float red[4][128];
  __shared__ f32x4 red4[8][64];              // 8 KB
  __shared__ float wrow[128];
  __shared__ float mred[8], zred[8];
  char* Ab = (char*)A;

  if (tid < 128){ bnsc[tid] = bns[s0 + tid]; bnsh[tid] = bnb[s0 + tid]; }

  float xhv[4];
  #pragma unroll
  for (int nt = 0; nt < 4; ++nt) xhv[nt] = xh[b * 256 + wn * 64 + nt * 16 + lr];

  const float* Abase = xhpre + ((size_t)b * S + s0) * Dd;

  // ---- prologue: stage K-step 0 (rows: w*16+i*4+kg, cols: lr*4 floats) ----
  #pragma unroll
  for (int i = 0; i < 4; ++i){
    int row = w * 16 + i * 4 + kg;
    float4 v = *reinterpret_cast<const float4*>(Abase + (size_t)row * Dd + lr * 4);
    union { _Float16 h[4]; uint2 u; } pk;
    pk.h[0]=(_Float16)v.x; pk.h[1]=(_Float16)v.y; pk.h[2]=(_Float16)v.z; pk.h[3]=(_Float16)v.w;
    int byte = (row * 512 + lr * 8) ^ ((row & 7) << 4);
    *reinterpret_cast<uint2*>(Ab + byte) = pk.u;
  }
  __syncthreads();

  f32x4 acc[4][4] = {};

  #pragma unroll
  for (int k0 = 0; k0 < 4; ++k0){
    // issue next-step A loads early (hide HBM/L2 latency under MFMA)
    float4 nv[4];
    if (k0 < 3){
      #pragma unroll
      for (int i = 0; i < 4; ++i){
        int row = w * 16 + i * 4 + kg;
        nv[i] = *reinterpret_cast<const float4*>(Abase + (size_t)row * Dd + (k0 + 1) * 64 + lr * 4);
      }
    }

    #pragma unroll
    for (int kk = 0; kk < 2; ++kk){
      const int q = k0 * 2 + kk;
      half8 afr[4], bfr[4];
      #pragma unroll
      for (int nt = 0; nt < 4; ++nt)
        bfr[nt] = *reinterpret_cast<const half8*>(Bp + ((size_t)((q * 16 + wn * 4 + nt) * 64 + lane)) * 8);
      #pragma unroll
      for (int mt = 0; mt < 4; ++mt){
        int row = wm * 64 + mt * 16 + lr;
        int byte = (row * 512 + k0 * 128 + kk * 64 + kg * 16) ^ ((row & 7) << 4);
        afr[mt] = *reinterpret_cast<const half8*>(Ab + byte);
      }
      #pragma unroll
      for (int mt = 0; mt < 4; ++mt)
        #pragma unroll
        for (int nt = 0; nt < 4; ++nt)
          acc[mt][nt] = __builtin_amdgcn_mfma_f32_16x16x32_f16(afr[mt], bfr[nt], acc[mt][nt], 0, 0, 0);
    }

    if (k0 < 3){
      #pragma unroll
      for (int i = 0; i < 4; ++i){
        int row = w * 16 + i * 4 + kg;
        union { _Float16 h[4]; uint2 u; } pk;
        pk.h[0]=(_Float16)nv[i].x; pk.h[1]=(_Float16)nv[i].y;
        pk.h[2]=(_Float16)nv[i].z; pk.h[3]=(_Float16)nv[i].w;
        int byte = (row * 512 + (k0 + 1) * 128 + lr * 8) ^ ((row & 7) << 4);
        *reinterpret_cast<uint2*>(Ab + byte) = pk.u;
      }
    }
    __syncthreads();
  }

  // ---- a_t epilogue: BN + tanh + dot(x_h); reduce 16 cols (lr), then 4 wn groups ----
  #pragma unroll
  for (int mt = 0; mt < 4; ++mt){
    #pragma unroll
    for (int r = 0; r < 4; ++r){
      int row = wm * 64 + mt * 16 + kg * 4 + r;   // C/D: col=lane&15, row=(lane>>4)*4+reg
      float sc = bnsc[row], sh = bnsh[row];
      float sum = 0.f;
      #pragma unroll
      for (int nt = 0; nt < 4; ++nt){
        float hv = fmaf(acc[mt][nt][r], sc, sh);
        sum = fmaf(tanh_fast(hv), xhv[nt], sum);
      }
      sum += __shfl_xor(sum, 1);
      sum += __shfl_xor(sum, 2);
      sum += __shfl_xor(sum, 4);
      sum += __shfl_xor(sum, 8);
      if (lr == 0) red[wn][row] = sum;
    }
  }
  __syncthreads();

  // ---- local softmax stats over the 128 rows ----
  float v = (tid < 128) ? (red[0][tid] + red[1][tid] + red[2][tid] + red[3][tid]) : -3.0e38f;
  float m_l = v;
  #pragma unroll
  for (int o = 1; o < 64; o <<= 1) m_l = fmaxf(m_l, __shfl_xor(m_l, o));
  if (lane == 0) mred[w] = m_l;
  __syncthreads();
  float m_c = mred[0];
  #pragma unroll
  for (int i = 1; i < 8; ++i) m_c = fmaxf(m_c, mred[i]);
  float wv = (tid < 128) ? __expf(v - m_c) : 0.0f;
  if (tid < 128) wrow[tid] = wv;
  float z_l = wv;
  #pragma unroll
  for (int o = 1; o < 64; o <<= 1) z_l += __shfl_xor(z_l, o);
  if (lane == 0) zred[w] = z_l;
  __syncthreads();

  // ---- weighted tile sum: P_c[d] = sum_rows wrow[row] * x[row][d], from LDS fp16 ----
  f32x4 pacc = {0.f, 0.f, 0.f, 0.f};
  #pragma unroll
  for (int r = 0; r < 16; ++r){
    int row = w * 16 + r;
    float wgt = wrow[row];
    int byte = (row * 512 + lane * 8) ^ ((row & 7) << 4);
    union { _Float16 h[4]; uint2 u; } pk;
    pk.u = *reinterpret_cast<const uint2*>(Ab + byte);
    pacc[0] = fmaf(wgt, (float)pk.h[0], pacc[0]);
    pacc[1] = fmaf(wgt, (float)pk.h[1], pacc[1]);
    pacc[2] = fmaf(wgt, (float)pk.h[2], pacc[2]);
    pacc[3] = fmaf(wgt, (float)pk.h[3], pacc[3]);
  }
  red4[w][lane] = pacc;
  __syncthreads();
  if (tid < 64){
    f32x4 r = red4[0][tid];
    #pragma unroll
    for (int i = 1; i < 8; ++i) r += red4[i][tid];
    *reinterpret_cast<f32x4*>(Pbuf + (size_t)bid * 256 + tid * 4) = r;
  }
  if (tid == 0){
    float z_c = 0.f;
    #pragma unroll
    for (int i = 0; i < 8; ++i) z_c += zred[i];
    mz[bid] = make_float2(m_c, z_c);
  }
}

// ---------------- combine 32 chunks per b: flash-style merge + W2 scale ----------------
__global__ __launch_bounds__(256) void k_combine(const float* __restrict__ Pbuf,
    const float2* __restrict__ mz, const float* __restrict__ W2, float* __restrict__ out){
  int b = blockIdx.x, d = threadIdx.x;
  __shared__ float2 smz[32];
  if (d < 32) smz[d] = mz[b * 32 + d];
  __syncthreads();
  float M = smz[0].x;
  #pragma unroll
  for (int c = 1; c < 32; ++c) M = fmaxf(M, smz[c].x);
  float Z = 0.f, acc = 0.f;
  #pragma unroll
  for (int c = 0; c < 32; ++c){
    float e = __expf(smz[c].x - M);
    Z += smz[c].y * e;
    acc = fmaf(e, Pbuf[(size_t)(b * 32 + c) * 256 + d], acc);
  }
  out[b * 256 + d] = acc * W2[d] / Z;
}

extern "C" void kernel_launch(void* const* d_in, const int* in_sizes, int n_in,
                              void* d_out, int out_size, void* d_ws, size_t ws_size,
                              hipStream_t stream){
  const float* x_h    = (const float*)d_in[0];
  const float* x_hpre = (const float*)d_in[1];
  const float* W1     = (const float*)d_in[2];
  const float* W2     = (const float*)d_in[3];
  const float* gamma  = (const float*)d_in[4];
  const float* beta   = (const float*)d_in[5];
  const float* rmean  = (const float*)d_in[6];
  const float* rvar   = (const float*)d_in[7];
  float* out = (float*)d_out;

  char* ws = (char*)d_ws;
  _Float16* Bp = (_Float16*)(ws);           // 131072 B (fragment-ordered W1)
  float* bns   = (float*)(ws + 131072);     // 16 KB
  float* bnb   = (float*)(ws + 147456);     // 16 KB
  float* Pbuf  = (float*)(ws + 163840);     // 2 MB (64*32 chunks * 256 f32)
  float2* mzb  = (float2*)(ws + 2260992);   // 16 KB

  hipLaunchKernelGGL(k_prep,    dim3(256),  dim3(256), 0, stream, W1, gamma, beta, rmean, rvar, Bp, bns, bnb);
  hipLaunchKernelGGL(k_fused,   dim3(2048), dim3(512), 0, stream, x_h, x_hpre, Bp, bns, bnb, Pbuf, mzb);
  hipLaunchKernelGGL(k_combine, dim3(64),   dim3(256), 0, stream, Pbuf, mzb, W2, out);
}

// Round 5
// 97.755 us; speedup vs baseline: 1.4077x; 1.4077x over previous
//
#include <hip/hip_runtime.h>

#define BN_EPS 1e-5f

typedef _Float16 half8 __attribute__((ext_vector_type(8)));
typedef float f32x4 __attribute__((ext_vector_type(4)));

__device__ __forceinline__ float tanh_fast(float x){
  float e = __expf(2.0f * x);
  return 1.0f - 2.0f / (e + 1.0f);
}

// ---------------- prep: W1 -> fp16 in MFMA-fragment order + BN scale/shift ----------------
// Fragment (q,c): q = k-chunk (32 k each, 0..7), c = col-block (16 e each, 0..15).
// lane l = kg*16+lr holds 8 halves: e = c*16+lr, d = q*32+kg*8+j.
__global__ __launch_bounds__(256) void k_prep(const float* __restrict__ W1,
    const float* __restrict__ gamma, const float* __restrict__ beta,
    const float* __restrict__ rmean, const float* __restrict__ rvar,
    _Float16* __restrict__ Bp2, float* __restrict__ bns, float* __restrict__ bnb){
  int i = blockIdx.x * 256 + threadIdx.x;   // 0..65535
  int j  = i & 7;
  int l  = (i >> 3) & 63;
  int c  = (i >> 9) & 15;
  int q  = (i >> 13) & 7;
  int lr = l & 15, kg = l >> 4;
  int e  = c * 16 + lr;
  int d  = q * 32 + kg * 8 + j;
  Bp2[i] = (_Float16)W1[e * 256 + d];
  if (i < 4096){
    float sc = gamma[i] * rsqrtf(rvar[i] + BN_EPS);
    bns[i] = sc;
    bnb[i] = beta[i] - rmean[i] * sc;
  }
}

// ---------------- fused GEMM + BN + tanh + dot(x_h) + local softmax + weighted tile sum ----------------
// 256 thr (4 waves), tile BM=64 s-rows x BN=256 e-cols, K=256, BK=64 (4 steps).
// LDS ~38.6KB -> 4 resident blocks/CU (4 independent barrier domains hide each
// other's load latency). A tile: FULL 64x256 fp16, XOR-swizzled, K-steps fill
// disjoint columns so the tile survives for the weighted-sum epilogue.
// B: register-direct coalesced fragment loads from L2. Wave w owns cols [64w,64w+64).
__global__ __launch_bounds__(256) void k_fused(const float* __restrict__ xh,
    const float* __restrict__ xhpre, const _Float16* __restrict__ Bp,
    const float* __restrict__ bns, const float* __restrict__ bnb,
    float* __restrict__ Pbuf, float2* __restrict__ mz){
  constexpr int S = 4096, Dd = 256;
  const int bid = blockIdx.x;       // 64 b * 64 chunks
  const int b  = bid >> 6;
  const int s0 = (bid & 63) * 64;
  const int tid = threadIdx.x;
  const int lane = tid & 63;
  const int w = tid >> 6;        // 0..3 = col-block owner
  const int kg = lane >> 4;      // 0..3
  const int lr = lane & 15;      // 0..15

  __shared__ _Float16 A[64 * 256];           // 32 KB, XOR-swizzled rows
  __shared__ float bnsc[64], bnsh[64];
  __shared__ float red[4][64];
  __shared__ f32x4 red4[4][64];              // 4 KB
  __shared__ float wrow[64];
  char* Ab = (char*)A;

  if (tid < 64){ bnsc[tid] = bns[s0 + tid]; bnsh[tid] = bnb[s0 + tid]; }

  float xhv[4];
  #pragma unroll
  for (int nt = 0; nt < 4; ++nt) xhv[nt] = xh[b * 256 + w * 64 + nt * 16 + lr];

  const float* Abase = xhpre + ((size_t)b * S + s0) * Dd;

  // ---- prologue: stage K-step 0 (wave w rows w*16+i*4+kg, cols lr*4 floats) ----
  {
    int row = w * 16 + kg;
    float4 v = *reinterpret_cast<const float4*>(Abase + (size_t)row * Dd + lr * 4);
    union { _Float16 h[4]; uint2 u; } pk;
    pk.h[0]=(_Float16)v.x; pk.h[1]=(_Float16)v.y; pk.h[2]=(_Float16)v.z; pk.h[3]=(_Float16)v.w;
    int byte = (row * 512 + lr * 8) ^ ((row & 7) << 4);
    *reinterpret_cast<uint2*>(Ab + byte) = pk.u;
  }
  #pragma unroll
  for (int i = 1; i < 4; ++i){
    int row = w * 16 + i * 4 + kg;
    float4 v = *reinterpret_cast<const float4*>(Abase + (size_t)row * Dd + lr * 4);
    union { _Float16 h[4]; uint2 u; } pk;
    pk.h[0]=(_Float16)v.x; pk.h[1]=(_Float16)v.y; pk.h[2]=(_Float16)v.z; pk.h[3]=(_Float16)v.w;
    int byte = (row * 512 + lr * 8) ^ ((row & 7) << 4);
    *reinterpret_cast<uint2*>(Ab + byte) = pk.u;
  }
  __syncthreads();

  f32x4 acc[4][4] = {};

  #pragma unroll
  for (int k0 = 0; k0 < 4; ++k0){
    // issue next-step A loads early (hide HBM/L3 latency under MFMA)
    float4 nv[4];
    if (k0 < 3){
      #pragma unroll
      for (int i = 0; i < 4; ++i){
        int row = w * 16 + i * 4 + kg;
        nv[i] = *reinterpret_cast<const float4*>(Abase + (size_t)row * Dd + (k0 + 1) * 64 + lr * 4);
      }
    }

    #pragma unroll
    for (int kk = 0; kk < 2; ++kk){
      const int q = k0 * 2 + kk;
      half8 afr[4], bfr[4];
      #pragma unroll
      for (int nt = 0; nt < 4; ++nt)
        bfr[nt] = *reinterpret_cast<const half8*>(Bp + ((size_t)((q * 16 + w * 4 + nt) * 64 + lane)) * 8);
      #pragma unroll
      for (int mt = 0; mt < 4; ++mt){
        int row = mt * 16 + lr;
        int byte = (row * 512 + k0 * 128 + kk * 64 + kg * 16) ^ ((row & 7) << 4);
        afr[mt] = *reinterpret_cast<const half8*>(Ab + byte);
      }
      #pragma unroll
      for (int mt = 0; mt < 4; ++mt)
        #pragma unroll
        for (int nt = 0; nt < 4; ++nt)
          acc[mt][nt] = __builtin_amdgcn_mfma_f32_16x16x32_f16(afr[mt], bfr[nt], acc[mt][nt], 0, 0, 0);
    }

    if (k0 < 3){
      #pragma unroll
      for (int i = 0; i < 4; ++i){
        int row = w * 16 + i * 4 + kg;
        union { _Float16 h[4]; uint2 u; } pk;
        pk.h[0]=(_Float16)nv[i].x; pk.h[1]=(_Float16)nv[i].y;
        pk.h[2]=(_Float16)nv[i].z; pk.h[3]=(_Float16)nv[i].w;
        int byte = (row * 512 + (k0 + 1) * 128 + lr * 8) ^ ((row & 7) << 4);
        *reinterpret_cast<uint2*>(Ab + byte) = pk.u;
      }
    }
    __syncthreads();
  }

  // ---- a_t epilogue: BN + tanh + dot(x_h); reduce 16 cols (lr) per wave ----
  #pragma unroll
  for (int mt = 0; mt < 4; ++mt){
    #pragma unroll
    for (int r = 0; r < 4; ++r){
      int row = mt * 16 + kg * 4 + r;   // C/D: col=lane&15, row=(lane>>4)*4+reg
      float sc = bnsc[row], sh = bnsh[row];
      float sum = 0.f;
      #pragma unroll
      for (int nt = 0; nt < 4; ++nt){
        float hv = fmaf(acc[mt][nt][r], sc, sh);
        sum = fmaf(tanh_fast(hv), xhv[nt], sum);
      }
      sum += __shfl_xor(sum, 1);
      sum += __shfl_xor(sum, 2);
      sum += __shfl_xor(sum, 4);
      sum += __shfl_xor(sum, 8);
      if (lr == 0) red[w][row] = sum;
    }
  }
  __syncthreads();

  // ---- local softmax stats over 64 rows (wave 0 only: tid==lane<64) ----
  if (w == 0){
    float v = red[0][lane] + red[1][lane] + red[2][lane] + red[3][lane];
    float m_c = v;
    #pragma unroll
    for (int o = 1; o < 64; o <<= 1) m_c = fmaxf(m_c, __shfl_xor(m_c, o));
    float wv = __expf(v - m_c);
    wrow[lane] = wv;
    float z_c = wv;
    #pragma unroll
    for (int o = 1; o < 64; o <<= 1) z_c += __shfl_xor(z_c, o);
    if (lane == 0) mz[bid] = make_float2(m_c, z_c);
  }
  __syncthreads();

  // ---- weighted tile sum: P_c[d] = sum_rows wrow[row]*x[row][d], from LDS fp16 ----
  f32x4 pacc = {0.f, 0.f, 0.f, 0.f};
  #pragma unroll
  for (int r = 0; r < 16; ++r){
    int row = w * 16 + r;
    float wgt = wrow[row];
    int byte = (row * 512 + lane * 8) ^ ((row & 7) << 4);
    union { _Float16 h[4]; uint2 u; } pk;
    pk.u = *reinterpret_cast<const uint2*>(Ab + byte);
    pacc[0] = fmaf(wgt, (float)pk.h[0], pacc[0]);
    pacc[1] = fmaf(wgt, (float)pk.h[1], pacc[1]);
    pacc[2] = fmaf(wgt, (float)pk.h[2], pacc[2]);
    pacc[3] = fmaf(wgt, (float)pk.h[3], pacc[3]);
  }
  red4[w][lane] = pacc;
  __syncthreads();
  if (tid < 64){
    f32x4 r = red4[0][tid] + red4[1][tid] + red4[2][tid] + red4[3][tid];
    *reinterpret_cast<f32x4*>(Pbuf + (size_t)bid * 256 + tid * 4) = r;
  }
}

// ---------------- combine 64 chunks per b: flash-style merge + W2 scale ----------------
__global__ __launch_bounds__(256) void k_combine(const float* __restrict__ Pbuf,
    const float2* __restrict__ mz, const float* __restrict__ W2, float* __restrict__ out){
  int b = blockIdx.x, d = threadIdx.x;
  __shared__ float2 smz[64];
  if (d < 64) smz[d] = mz[b * 64 + d];
  __syncthreads();
  float M = smz[0].x;
  #pragma unroll
  for (int c = 1; c < 64; ++c) M = fmaxf(M, smz[c].x);
  float Z = 0.f, acc = 0.f;
  #pragma unroll 8
  for (int c = 0; c < 64; ++c){
    float e = __expf(smz[c].x - M);
    Z += smz[c].y * e;
    acc = fmaf(e, Pbuf[(size_t)(b * 64 + c) * 256 + d], acc);
  }
  out[b * 256 + d] = acc * W2[d] / Z;
}

extern "C" void kernel_launch(void* const* d_in, const int* in_sizes, int n_in,
                              void* d_out, int out_size, void* d_ws, size_t ws_size,
                              hipStream_t stream){
  const float* x_h    = (const float*)d_in[0];
  const float* x_hpre = (const float*)d_in[1];
  const float* W1     = (const float*)d_in[2];
  const float* W2     = (const float*)d_in[3];
  const float* gamma  = (const float*)d_in[4];
  const float* beta   = (const float*)d_in[5];
  const float* rmean  = (const float*)d_in[6];
  const float* rvar   = (const float*)d_in[7];
  float* out = (float*)d_out;

  char* ws = (char*)d_ws;
  _Float16* Bp = (_Float16*)(ws);            // 131072 B (fragment-ordered W1)
  float* bns   = (float*)(ws + 131072);      // 16 KB
  float* bnb   = (float*)(ws + 147456);      // 16 KB
  float* Pbuf  = (float*)(ws + 163840);      // 4 MB (64*64 chunks * 256 f32)
  float2* mzb  = (float2*)(ws + 4358144);    // 32 KB  (total ~4.4 MB)

  hipLaunchKernelGGL(k_prep,    dim3(256),  dim3(256), 0, stream, W1, gamma, beta, rmean, rvar, Bp, bns, bnb);
  hipLaunchKernelGGL(k_fused,   dim3(4096), dim3(256), 0, stream, x_h, x_hpre, Bp, bns, bnb, Pbuf, mzb);
  hipLaunchKernelGGL(k_combine, dim3(64),   dim3(256), 0, stream, Pbuf, mzb, W2, out);
}